// Round 7
// baseline (405.119 us; speedup 1.0000x reference)
//
#include <hip/hip_runtime.h>

// ---------------------------------------------------------------------------
// ScaleDotProductAttention: q=Q@Wq^T+bq; k=K@Wk^T+bk; v=V@Wv^T+bv
// S = q@k^T/32 (mask==1 -> -inf), P=softmax(S), out = P@v
// B=8, L1=L2=2048, D=E=1024. bf16 MFMA 16x16x32, fp32 accum.
// Round 7: fp32->bf16 convert FUSED into projection A-staging (reg-staged
// float4 loads -> f2bf -> swizzled ds_write_b128), killing the three 96MB
// cvt passes. qk/pv GEMM bodies unchanged from round 6.
// ---------------------------------------------------------------------------

using u16 = unsigned short;
using frag_ab = __attribute__((ext_vector_type(8))) short;   // 8 bf16 (4 VGPRs)
using frag_cd = __attribute__((ext_vector_type(4))) float;   // 4 fp32

#define BAR() asm volatile("s_barrier" ::: "memory")
#define WAITV(n) asm volatile("s_waitcnt vmcnt(" #n ")" ::: "memory")
#define WAITLGKM0() do { asm volatile("s_waitcnt lgkmcnt(0)" ::: "memory"); \
                         __builtin_amdgcn_sched_barrier(0); } while (0)
#define L(d, ab, h) (lds + (((d) * 4) + ((ab) * 2) + (h)) * 8192)

__device__ __forceinline__ u16 f2bf(float f) {
  union { float f; unsigned u; } c; c.f = f;
  unsigned u = c.u;
  return (u16)((u + 0x7FFFu + ((u >> 16) & 1u)) >> 16);   // RNE
}

__device__ __forceinline__ frag_ab pack8(float4 x, float4 y) {
  frag_ab p;
  p[0] = (short)f2bf(x.x); p[1] = (short)f2bf(x.y);
  p[2] = (short)f2bf(x.z); p[3] = (short)f2bf(x.w);
  p[4] = (short)f2bf(y.x); p[5] = (short)f2bf(y.y);
  p[6] = (short)f2bf(y.z); p[7] = (short)f2bf(y.w);
  return p;
}

__device__ __forceinline__ void async_ld16(const void* g, void* l) {
  __builtin_amdgcn_global_load_lds(
      (const __attribute__((address_space(1))) unsigned*)g,
      (__attribute__((address_space(3))) unsigned*)l, 16, 0, 0);
}

// fp32 -> bf16 bits, 4 elems/thread (weights only now)
__global__ void cvt_f32_bf16(const float* __restrict__ in, u16* __restrict__ out, long n) {
  long i = ((long)blockIdx.x * 256 + threadIdx.x) * 4;
  if (i >= n) return;
  float4 v = *reinterpret_cast<const float4*>(in + i);
  ushort4 o = make_ushort4(f2bf(v.x), f2bf(v.y), f2bf(v.z), f2bf(v.w));
  *reinterpret_cast<ushort4*>(out + i) = o;
}

// Stage one 128x64 bf16 half-tile via global_load_lds (linear dest,
// 3-bit XOR swizzle pre-applied to the GLOBAL source 16B-slot).
__device__ __forceinline__ void stage_half(const u16* __restrict__ g_rowbase,
                                           long Kstr, u16* l_half,
                                           int wave, int lane) {
  const int t = wave * 64 + lane;
  #pragma unroll
  for (int i = 0; i < 2; i++) {
    const int row = i * 64 + (t >> 3);
    const int cb  = (t & 7) * 16;
    const int cbs = cb ^ ((row & 7) << 4);
    async_ld16(g_rowbase + (long)row * Kstr + (cbs >> 1),
               l_half + i * 4096 + wave * 512);
  }
}

// swizzled fragment read: 8 bf16 at (row r, k..k+7) of a [128][64] half
__device__ __forceinline__ frag_ab ld_frag(const u16* half_base, int r, int k) {
  const int idx = r * 64 + (k ^ ((r & 7) << 3));
  return *reinterpret_cast<const frag_ab*>(half_base + idx);
}

// swizzled ds_write of 8 bf16 at (row r, 16B-slot s) of a [128][64] half
__device__ __forceinline__ void st_frag(u16* half_base, int r, int s, frag_ab v) {
  *reinterpret_cast<frag_ab*>(half_base + r * 64 + ((s ^ (r & 7)) << 3)) = v;
}

// C = scale * (A @ Bt^T) + bias.  Bt:[N][K] bf16 row-major.
// AF32=false: A bf16, gld_lds-staged (round-6 path, unchanged).
// AF32=true:  A fp32, reg-staged with fused f2bf (projections).
// OUT_MODE: 0 fp32 C[M][N]; 1 bf16 C[M][N]; 2 bf16 vT[b][n][l2] (b=row>>11).
template<int OUT_MODE, bool AF32>
__device__ __forceinline__ void
gemm256_body(const void* __restrict__ Avoid, const u16* __restrict__ Bt,
             void* __restrict__ Cout, const float* __restrict__ bias,
             int M, int N, int K, long sA, long sB, long sC, float scale,
             u16* lds)
{
  const int gx = gridDim.x, gy = gridDim.y, gz = gridDim.z;
  const int nwg = gx * gy * gz;
  const int lin = ((int)blockIdx.z * gy + blockIdx.y) * gx + blockIdx.x;
  const int q8 = nwg >> 3, r8 = nwg & 7;
  const int xcd = lin & 7, idx8 = lin >> 3;
  const int swz = (xcd < r8 ? xcd * (q8 + 1) : r8 * (q8 + 1) + (xcd - r8) * q8) + idx8;
  const int z = swz / (gx * gy);
  const int rem = swz % (gx * gy);
  const int m0 = (rem / gx) * 256;
  const int n0 = (rem % gx) * 256;

  const u16*   Ab16 = AF32 ? nullptr : (const u16*)Avoid + (long)z * sA;
  const float* Abf  = AF32 ? (const float*)Avoid + (long)z * sA : nullptr;
  const u16* Bb = Bt + (long)z * sB;

  const int tid = threadIdx.x;
  const int wave = tid >> 6, lane = tid & 63;
  const int wm = wave >> 2;
  const int wn = wave & 3;
  const int ln15 = lane & 15, kof = (lane >> 4) * 8;
  const int rB0 = (wn & 1) * 64;
  const int NT = K >> 6;
  const int sr = tid >> 3;         // staging row 0..63
  const int ss = tid & 7;          // staging 16B slot

  frag_cd acc[8][4];
  #pragma unroll
  for (int i = 0; i < 8; i++)
    #pragma unroll
    for (int j = 0; j < 4; j++)
      acc[i][j] = (frag_cd){0.f, 0.f, 0.f, 0.f};

  // ---- prologue ----
  if (AF32) {
    const float* a0 = Abf + (long)(m0 + sr) * K + ss * 8;
    float4 c0a = *(const float4*)(a0);
    float4 c0b = *(const float4*)(a0 + 4);
    float4 c1a = *(const float4*)(a0 +  64L * K);
    float4 c1b = *(const float4*)(a0 +  64L * K + 4);
    float4 c2a = *(const float4*)(a0 + 128L * K);
    float4 c2b = *(const float4*)(a0 + 128L * K + 4);
    float4 c3a = *(const float4*)(a0 + 192L * K);
    float4 c3b = *(const float4*)(a0 + 192L * K + 4);
    stage_half(Bb + (long)(n0 +   0) * K, K, L(0, 1, 0), wave, lane);
    stage_half(Bb + (long)(n0 + 128) * K, K, L(0, 1, 1), wave, lane);
    {
      const int t1 = (1 < NT) ? 1 : 0;
      stage_half(Bb + (long)(n0 +   0) * K + t1 * 64, K, L(1, 1, 0), wave, lane);
      stage_half(Bb + (long)(n0 + 128) * K + t1 * 64, K, L(1, 1, 1), wave, lane);
    }
    st_frag(L(0, 0, 0), sr,      ss, pack8(c0a, c0b));
    st_frag(L(0, 0, 0), sr + 64, ss, pack8(c1a, c1b));
    st_frag(L(0, 0, 1), sr,      ss, pack8(c2a, c2b));
    st_frag(L(0, 0, 1), sr + 64, ss, pack8(c3a, c3b));
    WAITV(0);
    WAITLGKM0();
    BAR();
  } else {
    stage_half(Ab16 + (long)(m0 +   0) * K, K, L(0, 0, 0), wave, lane);
    stage_half(Ab16 + (long)(m0 + 128) * K, K, L(0, 0, 1), wave, lane);
    stage_half(Bb + (long)(n0 +   0) * K, K, L(0, 1, 0), wave, lane);
    stage_half(Bb + (long)(n0 + 128) * K, K, L(0, 1, 1), wave, lane);
    {
      const int t1 = (1 < NT) ? 1 : 0;
      stage_half(Bb + (long)(n0 +   0) * K + t1 * 64, K, L(1, 1, 0), wave, lane);
      stage_half(Bb + (long)(n0 + 128) * K + t1 * 64, K, L(1, 1, 1), wave, lane);
    }
    WAITV(4);
    BAR();
  }

  for (int t = 0; t < NT; ++t) {
    const int d = t & 1;
    const u16* Al = L(d, 0, wm);
    const u16* Bl = L(d, 1, wn >> 1);
    const int tA = (t + 1 < NT) ? t + 1 : NT - 1;
    const int tB = (t + 2 < NT) ? t + 2 : NT - 1;

    frag_ab bf[4][2], af[2][2];
    float4 c0a, c0b, c1a, c1b, c2a, c2b, c3a, c3b;

    // ------ q0: 12 ds_reads; issue A(t+1) chunks 0,1; mfma am0-1 ------
    #pragma unroll
    for (int bn = 0; bn < 4; ++bn)
      #pragma unroll
      for (int kk = 0; kk < 2; ++kk)
        bf[bn][kk] = ld_frag(Bl, rB0 + bn * 16 + ln15, kk * 32 + kof);
    #pragma unroll
    for (int am = 0; am < 2; ++am)
      #pragma unroll
      for (int kk = 0; kk < 2; ++kk)
        af[am][kk] = ld_frag(Al, am * 16 + ln15, kk * 32 + kof);
    if (AF32) {
      const float* ap = Abf + (long)(m0 + sr) * K + tA * 64 + ss * 8;
      c0a = *(const float4*)(ap);
      c0b = *(const float4*)(ap + 4);
      c1a = *(const float4*)(ap + 64L * K);
      c1b = *(const float4*)(ap + 64L * K + 4);
    } else {
      stage_half(Ab16 + (long)(m0 +   0) * K + tA * 64, K, L(d ^ 1, 0, 0), wave, lane);
      stage_half(Ab16 + (long)(m0 + 128) * K + tA * 64, K, L(d ^ 1, 0, 1), wave, lane);
    }
    BAR();
    __builtin_amdgcn_s_setprio(1);
    #pragma unroll
    for (int am = 0; am < 2; ++am)
      #pragma unroll
      for (int bn = 0; bn < 4; ++bn)
        #pragma unroll
        for (int kk = 0; kk < 2; ++kk)
          acc[am][bn] = __builtin_amdgcn_mfma_f32_16x16x32_bf16(af[am][kk], bf[bn][kk], acc[am][bn], 0, 0, 0);
    __builtin_amdgcn_s_setprio(0);
    BAR();

    // ------ q1: 4 ds_reads; issue A chunks 2,3; write chunks 0,1;
    //          stage Bh0(t+2); mfma am2-3 ------
    #pragma unroll
    for (int am = 0; am < 2; ++am)
      #pragma unroll
      for (int kk = 0; kk < 2; ++kk)
        af[am][kk] = ld_frag(Al, (2 + am) * 16 + ln15, kk * 32 + kof);
    if (AF32) {
      const float* ap = Abf + (long)(m0 + 128 + sr) * K + tA * 64 + ss * 8;
      c2a = *(const float4*)(ap);
      c2b = *(const float4*)(ap + 4);
      c3a = *(const float4*)(ap + 64L * K);
      c3b = *(const float4*)(ap + 64L * K + 4);
    }
    stage_half(Bb + (long)(n0 + 0) * K + tB * 64, K, L(d, 1, 0), wave, lane);
    if (AF32) {
      st_frag(L(d ^ 1, 0, 0), sr,      ss, pack8(c0a, c0b));
      st_frag(L(d ^ 1, 0, 0), sr + 64, ss, pack8(c1a, c1b));
    }
    BAR();
    __builtin_amdgcn_s_setprio(1);
    #pragma unroll
    for (int am = 0; am < 2; ++am)
      #pragma unroll
      for (int bn = 0; bn < 4; ++bn)
        #pragma unroll
        for (int kk = 0; kk < 2; ++kk)
          acc[2 + am][bn] = __builtin_amdgcn_mfma_f32_16x16x32_bf16(af[am][kk], bf[bn][kk], acc[2 + am][bn], 0, 0, 0);
    __builtin_amdgcn_s_setprio(0);
    BAR();

    // ------ q2: 4 ds_reads; stage Bh1(t+2); write chunks 2,3 + drain;
    //          mfma am4-5 ------
    #pragma unroll
    for (int am = 0; am < 2; ++am)
      #pragma unroll
      for (int kk = 0; kk < 2; ++kk)
        af[am][kk] = ld_frag(Al, (4 + am) * 16 + ln15, kk * 32 + kof);
    stage_half(Bb + (long)(n0 + 128) * K + tB * 64, K, L(d, 1, 1), wave, lane);
    if (AF32) {
      st_frag(L(d ^ 1, 0, 1), sr,      ss, pack8(c2a, c2b));
      st_frag(L(d ^ 1, 0, 1), sr + 64, ss, pack8(c3a, c3b));
      WAITLGKM0();   // commit A-writes (readers are 2+ barriers away)
    }
    BAR();
    __builtin_amdgcn_s_setprio(1);
    #pragma unroll
    for (int am = 0; am < 2; ++am)
      #pragma unroll
      for (int bn = 0; bn < 4; ++bn)
        #pragma unroll
        for (int kk = 0; kk < 2; ++kk)
          acc[4 + am][bn] = __builtin_amdgcn_mfma_f32_16x16x32_bf16(af[am][kk], bf[bn][kk], acc[4 + am][bn], 0, 0, 0);
    __builtin_amdgcn_s_setprio(0);
    BAR();

    // ------ q3: 4 ds_reads; mfma am6-7; tile-end ------
    #pragma unroll
    for (int am = 0; am < 2; ++am)
      #pragma unroll
      for (int kk = 0; kk < 2; ++kk)
        af[am][kk] = ld_frag(Al, (6 + am) * 16 + ln15, kk * 32 + kof);
    BAR();
    __builtin_amdgcn_s_setprio(1);
    #pragma unroll
    for (int am = 0; am < 2; ++am)
      #pragma unroll
      for (int bn = 0; bn < 4; ++bn)
        #pragma unroll
        for (int kk = 0; kk < 2; ++kk)
          acc[6 + am][bn] = __builtin_amdgcn_mfma_f32_16x16x32_bf16(af[am][kk], bf[bn][kk], acc[6 + am][bn], 0, 0, 0);
    __builtin_amdgcn_s_setprio(0);
    if (!AF32) { WAITV(4); }
    BAR();
  }

  WAITV(0);
  BAR();

  const int cl = lane & 15;
  const int rb = (lane >> 4) * 4;
  #pragma unroll
  for (int bn = 0; bn < 4; ++bn) {
    const int gcol = n0 + wn * 64 + bn * 16 + cl;
    const float badd = bias ? bias[gcol] : 0.f;
    #pragma unroll
    for (int am = 0; am < 8; ++am) {
      #pragma unroll
      for (int r = 0; r < 4; ++r) {
        const int grow = m0 + wm * 128 + am * 16 + rb + r;
        const float val = acc[am][bn][r] * scale + badd;
        if (OUT_MODE == 0) {
          ((float*)Cout)[(long)z * sC + (long)grow * N + gcol] = val;
        } else if (OUT_MODE == 1) {
          ((u16*)Cout)[(long)z * sC + (long)grow * N + gcol] = f2bf(val);
        } else {
          const int bb = grow >> 11, l2 = grow & 2047;
          ((u16*)Cout)[((long)bb * N + gcol) * 2048 + l2] = f2bf(val);
        }
      }
    }
  }
}

__global__ void __launch_bounds__(512, 1)
proj_gemm(const void* A, const u16* Bt, void* C, const float* bias,
          int M, int N, int K, long sA, long sB, long sC, float scale) {
  __shared__ u16 lds[8 * 8192];
  gemm256_body<1, true>(A, Bt, C, bias, M, N, K, sA, sB, sC, scale, lds);
}
__global__ void __launch_bounds__(512, 1)
projv_gemm(const void* A, const u16* Bt, void* C, const float* bias,
           int M, int N, int K, long sA, long sB, long sC, float scale) {
  __shared__ u16 lds[8 * 8192];
  gemm256_body<2, true>(A, Bt, C, bias, M, N, K, sA, sB, sC, scale, lds);
}
__global__ void __launch_bounds__(512, 2)
qk_gemm(const void* A, const u16* Bt, void* C, const float* bias,
        int M, int N, int K, long sA, long sB, long sC, float scale) {
  __shared__ u16 lds[8 * 8192];
  gemm256_body<0, false>(A, Bt, C, bias, M, N, K, sA, sB, sC, scale, lds);
}
__global__ void __launch_bounds__(512, 2)
pv_gemm(const void* A, const u16* Bt, void* C, const float* bias,
        int M, int N, int K, long sA, long sB, long sC, float scale) {
  __shared__ u16 lds[8 * 8192];
  gemm256_body<0, false>(A, Bt, C, bias, M, N, K, sA, sB, sC, scale, lds);
}

// softmax over a slab: blockIdx.x = row in [0, NB*2048); mask batch = row>>11
__global__ void softmax_rows(const float* __restrict__ S, const int* __restrict__ Km,
                             u16* __restrict__ P)
{
  const long row = blockIdx.x;
  const int b = (int)(row >> 11);
  const float* s = S + row * 2048;
  const int* mask = Km + (long)b * 2048;
  u16* p = P + row * 2048;

  const int t = threadIdx.x;
  const int base = t * 8;

  float4 v0 = *reinterpret_cast<const float4*>(s + base);
  float4 v1 = *reinterpret_cast<const float4*>(s + base + 4);
  int4 mA = *reinterpret_cast<const int4*>(mask + base);
  int4 mB = *reinterpret_cast<const int4*>(mask + base + 4);

  float vals[8] = {v0.x, v0.y, v0.z, v0.w, v1.x, v1.y, v1.z, v1.w};
  const int mk[8] = {mA.x, mA.y, mA.z, mA.w, mB.x, mB.y, mB.z, mB.w};

  float mx = -3.0e38f;
  #pragma unroll
  for (int i = 0; i < 8; i++) if (!mk[i]) mx = fmaxf(mx, vals[i]);
  #pragma unroll
  for (int off = 32; off > 0; off >>= 1) mx = fmaxf(mx, __shfl_xor(mx, off));

  __shared__ float redm[4], reds[4];
  const int wave = t >> 6, lane = t & 63;
  if (lane == 0) redm[wave] = mx;
  __syncthreads();
  mx = fmaxf(fmaxf(redm[0], redm[1]), fmaxf(redm[2], redm[3]));

  float e[8]; float sum = 0.f;
  #pragma unroll
  for (int i = 0; i < 8; i++) { e[i] = mk[i] ? 0.f : __expf(vals[i] - mx); sum += e[i]; }
  #pragma unroll
  for (int off = 32; off > 0; off >>= 1) sum += __shfl_xor(sum, off);
  if (lane == 0) reds[wave] = sum;
  __syncthreads();
  sum = reds[0] + reds[1] + reds[2] + reds[3];
  const float inv = 1.f / sum;

  ushort4 o0 = make_ushort4(f2bf(e[0]*inv), f2bf(e[1]*inv), f2bf(e[2]*inv), f2bf(e[3]*inv));
  ushort4 o1 = make_ushort4(f2bf(e[4]*inv), f2bf(e[5]*inv), f2bf(e[6]*inv), f2bf(e[7]*inv));
  *reinterpret_cast<ushort4*>(p + base) = o0;
  *reinterpret_cast<ushort4*>(p + base + 4) = o1;
}

extern "C" void kernel_launch(void* const* d_in, const int* in_sizes, int n_in,
                              void* d_out, int out_size, void* d_ws, size_t ws_size,
                              hipStream_t stream) {
  (void)in_sizes; (void)n_in; (void)out_size;

  const float* Qin  = (const float*)d_in[0];
  const float* Kin  = (const float*)d_in[1];
  const float* Vin  = (const float*)d_in[2];
  const int*   Kmask = (const int*)d_in[3];
  const float* Wq = (const float*)d_in[4];
  const float* bq = (const float*)d_in[5];
  const float* Wk = (const float*)d_in[6];
  const float* bk = (const float*)d_in[7];
  const float* Wv = (const float*)d_in[8];
  const float* bv = (const float*)d_in[9];

  char* ws = (char*)d_ws;
  const size_t MB = 1024UL * 1024UL;
  const long NW = 1024L * 1024;
  const dim3 blk(256);
  const dim3 gblk(512);
  const float rs = 0.03125f;  // 1/sqrt(1024)

  if (ws_size >= 226 * MB) {
    // [0,32) qb  [32,64) kb  [64,96) vT  [96,160) P  [160,224) S(4 batches)
    // [224,226) Wb
    u16*  qb = (u16*)(ws);
    u16*  kb = (u16*)(ws + 32 * MB);
    u16*  vT = (u16*)(ws + 64 * MB);
    u16*  P  = (u16*)(ws + 96 * MB);
    float* S = (float*)(ws + 160 * MB);
    u16*  Wb = (u16*)(ws + 224 * MB);

    cvt_f32_bf16<<<dim3(NW / 1024), blk, 0, stream>>>(Wq, Wb, NW);
    proj_gemm<<<dim3(4, 64, 1), gblk, 0, stream>>>(Qin, Wb, qb, bq,
        16384, 1024, 1024, 0, 0, 0, 1.f);

    cvt_f32_bf16<<<dim3(NW / 1024), blk, 0, stream>>>(Wk, Wb, NW);
    proj_gemm<<<dim3(4, 64, 1), gblk, 0, stream>>>(Kin, Wb, kb, bk,
        16384, 1024, 1024, 0, 0, 0, 1.f);

    cvt_f32_bf16<<<dim3(NW / 1024), blk, 0, stream>>>(Wv, Wb, NW);
    projv_gemm<<<dim3(4, 64, 1), gblk, 0, stream>>>(Vin, Wb, vT, bv,
        16384, 1024, 1024, 0, 0, 0, 1.f);

    for (int h = 0; h < 2; h++) {
      const u16* qbH = qb + (long)(4 * h) * 2048 * 1024;
      const u16* kbH = kb + (long)(4 * h) * 2048 * 1024;
      qk_gemm<<<dim3(8, 8, 4), gblk, 0, stream>>>(qbH, kbH, S, nullptr,
          2048, 2048, 1024, 2048L * 1024, 2048L * 1024, 2048L * 2048, rs);
      softmax_rows<<<dim3(8192), blk, 0, stream>>>(
          S, Kmask + (long)(4 * h) * 2048, P + (long)(4 * h) * 2048 * 2048);
    }

    pv_gemm<<<dim3(4, 8, 8), gblk, 0, stream>>>(P, vT, d_out, nullptr,
        2048, 1024, 2048, 2048L * 2048, 1024L * 2048, 2048L * 1024, 1.f);
  } else if (ws_size >= 194 * MB) {
    u16*  qb = (u16*)(ws);
    u16*  kb = (u16*)(ws + 32 * MB);
    u16*  vT = (u16*)(ws + 64 * MB);
    u16*  P  = (u16*)(ws + 96 * MB);
    float* S = (float*)(ws + 160 * MB);
    u16*  Wb = (u16*)(ws + 192 * MB);

    cvt_f32_bf16<<<dim3(NW / 1024), blk, 0, stream>>>(Wq, Wb, NW);
    proj_gemm<<<dim3(4, 64, 1), gblk, 0, stream>>>(Qin, Wb, qb, bq,
        16384, 1024, 1024, 0, 0, 0, 1.f);
    cvt_f32_bf16<<<dim3(NW / 1024), blk, 0, stream>>>(Wk, Wb, NW);
    proj_gemm<<<dim3(4, 64, 1), gblk, 0, stream>>>(Kin, Wb, kb, bk,
        16384, 1024, 1024, 0, 0, 0, 1.f);
    cvt_f32_bf16<<<dim3(NW / 1024), blk, 0, stream>>>(Wv, Wb, NW);
    projv_gemm<<<dim3(4, 64, 1), gblk, 0, stream>>>(Vin, Wb, vT, bv,
        16384, 1024, 1024, 0, 0, 0, 1.f);

    for (int p = 0; p < 4; p++) {
      const u16* qbP = qb + (long)(2 * p) * 2048 * 1024;
      const u16* kbP = kb + (long)(2 * p) * 2048 * 1024;
      qk_gemm<<<dim3(8, 8, 2), gblk, 0, stream>>>(qbP, kbP, S, nullptr,
          2048, 2048, 1024, 2048L * 1024, 2048L * 1024, 2048L * 2048, rs);
      softmax_rows<<<dim3(4096), blk, 0, stream>>>(
          S, Kmask + (long)(2 * p) * 2048, P + (long)(2 * p) * 2048 * 2048);
    }

    pv_gemm<<<dim3(4, 8, 8), gblk, 0, stream>>>(P, vT, d_out, nullptr,
        2048, 1024, 2048, 2048L * 2048, 1024L * 2048, 2048L * 1024, 1.f);
  } else {
    // 98 MB fallback: per-batch S/P streaming
    u16*  qb = (u16*)(ws);
    u16*  kb = (u16*)(ws + 32 * MB);
    u16*  vT = (u16*)(ws + 64 * MB);
    float* S = (float*)(ws + 96 * MB + 2 * MB);
    u16*  P  = (u16*)(ws + 96 * MB + 18 * MB);
    u16*  Wb = (u16*)(ws + 96 * MB);

    cvt_f32_bf16<<<dim3(NW / 1024), blk, 0, stream>>>(Wq, Wb, NW);
    proj_gemm<<<dim3(4, 64, 1), gblk, 0, stream>>>(Qin, Wb, qb, bq,
        16384, 1024, 1024, 0, 0, 0, 1.f);
    cvt_f32_bf16<<<dim3(NW / 1024), blk, 0, stream>>>(Wk, Wb, NW);
    proj_gemm<<<dim3(4, 64, 1), gblk, 0, stream>>>(Kin, Wb, kb, bk,
        16384, 1024, 1024, 0, 0, 0, 1.f);
    cvt_f32_bf16<<<dim3(NW / 1024), blk, 0, stream>>>(Wv, Wb, NW);
    projv_gemm<<<dim3(4, 64, 1), gblk, 0, stream>>>(Vin, Wb, vT, bv,
        16384, 1024, 1024, 0, 0, 0, 1.f);

    for (int b = 0; b < 8; b++) {
      const u16* qbB = qb + (long)b * 2048 * 1024;
      const u16* kbB = kb + (long)b * 2048 * 1024;
      const u16* vTB = vT + (long)b * 1024 * 2048;
      float* outB = (float*)d_out + (long)b * 2048 * 1024;

      qk_gemm<<<dim3(8, 8, 1), gblk, 0, stream>>>(qbB, kbB, S, nullptr,
          2048, 2048, 1024, 0, 0, 0, rs);
      softmax_rows<<<dim3(2048), blk, 0, stream>>>(S, Kmask + (long)b * 2048, P);
      pv_gemm<<<dim3(4, 8, 1), gblk, 0, stream>>>(P, vTB, outB, nullptr,
          2048, 1024, 2048, 0, 0, 0, 1.f);
    }
  }
}

// Round 8
// 365.274 us; speedup vs baseline: 1.1091x; 1.1091x over previous
//
#include <hip/hip_runtime.h>

// ---------------------------------------------------------------------------
// ScaleDotProductAttention: q=Q@Wq^T+bq; k=K@Wk^T+bk; v=V@Wv^T+bv
// S = q@k^T/32 (mask==1 -> -inf), P=softmax(S), out = P@v
// B=8, L1=L2=2048, D=E=1024. bf16 MFMA 16x16x32, fp32 accum.
// Round 8: REVERT round-7 reg-staged convert fusion (latency-bound, -22us);
// restore round-6 GEMM body. NEW: S stored as fp16 (halves S round-trip
// traffic; all 8 batches fit the 64MB slab -> single qk/softmax/pv
// dispatches), input converts merged into one 3-way dispatch.
// ---------------------------------------------------------------------------

using u16 = unsigned short;
using frag_ab = __attribute__((ext_vector_type(8))) short;   // 8 bf16 (4 VGPRs)
using frag_cd = __attribute__((ext_vector_type(4))) float;   // 4 fp32

#define BAR() asm volatile("s_barrier" ::: "memory")
#define WAITV(n) asm volatile("s_waitcnt vmcnt(" #n ")" ::: "memory")
#define L(d, ab, h) (lds + (((d) * 4) + ((ab) * 2) + (h)) * 8192)

__device__ __forceinline__ u16 f2bf(float f) {
  union { float f; unsigned u; } c; c.f = f;
  unsigned u = c.u;
  return (u16)((u + 0x7FFFu + ((u >> 16) & 1u)) >> 16);   // RNE
}
__device__ __forceinline__ u16 f2h(float f) {
  union { _Float16 h; u16 u; } c; c.h = (_Float16)f; return c.u;
}
__device__ __forceinline__ float h2f(u16 u) {
  union { u16 u; _Float16 h; } c; c.u = u; return (float)c.h;
}

__device__ __forceinline__ void async_ld16(const void* g, void* l) {
  __builtin_amdgcn_global_load_lds(
      (const __attribute__((address_space(1))) unsigned*)g,
      (__attribute__((address_space(3))) unsigned*)l, 16, 0, 0);
}

// weights: fp32 -> bf16, 4 elems/thread
__global__ void cvt_f32_bf16(const float* __restrict__ in, u16* __restrict__ out, long n) {
  long i = ((long)blockIdx.x * 256 + threadIdx.x) * 4;
  if (i >= n) return;
  float4 v = *reinterpret_cast<const float4*>(in + i);
  *reinterpret_cast<ushort4*>(out + i) =
      make_ushort4(f2bf(v.x), f2bf(v.y), f2bf(v.z), f2bf(v.w));
}

// Q,K,V inputs in one dispatch: z selects source; dest stride 16M elements
__global__ void cvt3_f32_bf16(const float* __restrict__ q, const float* __restrict__ k,
                              const float* __restrict__ v, u16* __restrict__ out) {
  const float* in = blockIdx.z == 0 ? q : (blockIdx.z == 1 ? k : v);
  u16* o = out + (long)blockIdx.z * 16777216L;
  long i = ((long)blockIdx.x * 256 + threadIdx.x) * 4;
  float4 x = *reinterpret_cast<const float4*>(in + i);
  *reinterpret_cast<ushort4*>(o + i) =
      make_ushort4(f2bf(x.x), f2bf(x.y), f2bf(x.z), f2bf(x.w));
}

// Stage one 128x64 bf16 half-tile via global_load_lds (linear dest,
// 3-bit XOR swizzle pre-applied to the GLOBAL source 16B-slot).
__device__ __forceinline__ void stage_half(const u16* __restrict__ g_rowbase,
                                           long Kstr, u16* l_half,
                                           int wave, int lane) {
  const int t = wave * 64 + lane;
  #pragma unroll
  for (int i = 0; i < 2; i++) {
    const int row = i * 64 + (t >> 3);
    const int cb  = (t & 7) * 16;
    const int cbs = cb ^ ((row & 7) << 4);
    async_ld16(g_rowbase + (long)row * Kstr + (cbs >> 1),
               l_half + i * 4096 + wave * 512);
  }
}

// swizzled fragment read: 8 bf16 at (row r, k..k+7) of a [128][64] half
__device__ __forceinline__ frag_ab ld_frag(const u16* half_base, int r, int k) {
  const int idx = r * 64 + (k ^ ((r & 7) << 3));
  return *reinterpret_cast<const frag_ab*>(half_base + idx);
}

// C = scale * (A @ Bt^T) + bias.  A:[M][K] bf16, Bt:[N][K] bf16 row-major.
// OUT_MODE: 0 fp32 C[M][N]; 1 bf16 C[M][N]; 2 bf16 vT[b][n][l2] (b=row>>11);
//           3 fp16 C[M][N].
// 256x256 tile, BK=64, 8 waves (2M x 4N), 128KB LDS dbuf, ds_reads 12/4/4/4,
// A staged 4 phases ahead, B 5-7 phases ahead, one vmcnt(4) per K-tile.
template<int OUT_MODE>
__device__ __forceinline__ void
gemm256_body(const u16* __restrict__ A, const u16* __restrict__ Bt,
             void* __restrict__ Cout, const float* __restrict__ bias,
             int M, int N, int K, long sA, long sB, long sC, float scale,
             u16* lds)
{
  // bijective XCD swizzle over the FULL grid (z folded in)
  const int gx = gridDim.x, gy = gridDim.y, gz = gridDim.z;
  const int nwg = gx * gy * gz;
  const int lin = ((int)blockIdx.z * gy + blockIdx.y) * gx + blockIdx.x;
  const int q8 = nwg >> 3, r8 = nwg & 7;
  const int xcd = lin & 7, idx8 = lin >> 3;
  const int swz = (xcd < r8 ? xcd * (q8 + 1) : r8 * (q8 + 1) + (xcd - r8) * q8) + idx8;
  const int z = swz / (gx * gy);
  const int rem = swz % (gx * gy);
  const int m0 = (rem / gx) * 256;
  const int n0 = (rem % gx) * 256;

  const u16* Ab = A + (long)z * sA;
  const u16* Bb = Bt + (long)z * sB;

  const int tid = threadIdx.x;
  const int wave = tid >> 6, lane = tid & 63;
  const int wm = wave >> 2;
  const int wn = wave & 3;
  const int ln15 = lane & 15, kof = (lane >> 4) * 8;
  const int rB0 = (wn & 1) * 64;
  const int NT = K >> 6;

  frag_cd acc[8][4];
  #pragma unroll
  for (int i = 0; i < 8; i++)
    #pragma unroll
    for (int j = 0; j < 4; j++)
      acc[i][j] = (frag_cd){0.f, 0.f, 0.f, 0.f};

  // prologue: A(0), B(0) -> dbuf0; B(1) -> dbuf1; drain A0/B0
  stage_half(Ab + (long)(m0 +   0) * K, K, L(0, 0, 0), wave, lane);
  stage_half(Ab + (long)(m0 + 128) * K, K, L(0, 0, 1), wave, lane);
  stage_half(Bb + (long)(n0 +   0) * K, K, L(0, 1, 0), wave, lane);
  stage_half(Bb + (long)(n0 + 128) * K, K, L(0, 1, 1), wave, lane);
  {
    const int t1 = (1 < NT) ? 1 : 0;
    stage_half(Bb + (long)(n0 +   0) * K + t1 * 64, K, L(1, 1, 0), wave, lane);
    stage_half(Bb + (long)(n0 + 128) * K + t1 * 64, K, L(1, 1, 1), wave, lane);
  }
  WAITV(4);
  BAR();

  for (int t = 0; t < NT; ++t) {
    const int d = t & 1;
    const u16* Al = L(d, 0, wm);
    const u16* Bl = L(d, 1, wn >> 1);
    const int tA = (t + 1 < NT) ? t + 1 : NT - 1;
    const int tB = (t + 2 < NT) ? t + 2 : NT - 1;

    frag_ab bf[4][2], af[2][2];

    // q0: 12 reads; stage A(t+1) both halves; mfma am0-1
    #pragma unroll
    for (int bn = 0; bn < 4; ++bn)
      #pragma unroll
      for (int kk = 0; kk < 2; ++kk)
        bf[bn][kk] = ld_frag(Bl, rB0 + bn * 16 + ln15, kk * 32 + kof);
    #pragma unroll
    for (int am = 0; am < 2; ++am)
      #pragma unroll
      for (int kk = 0; kk < 2; ++kk)
        af[am][kk] = ld_frag(Al, am * 16 + ln15, kk * 32 + kof);
    stage_half(Ab + (long)(m0 +   0) * K + tA * 64, K, L(d ^ 1, 0, 0), wave, lane);
    stage_half(Ab + (long)(m0 + 128) * K + tA * 64, K, L(d ^ 1, 0, 1), wave, lane);
    BAR();
    __builtin_amdgcn_s_setprio(1);
    #pragma unroll
    for (int am = 0; am < 2; ++am)
      #pragma unroll
      for (int bn = 0; bn < 4; ++bn)
        #pragma unroll
        for (int kk = 0; kk < 2; ++kk)
          acc[am][bn] = __builtin_amdgcn_mfma_f32_16x16x32_bf16(af[am][kk], bf[bn][kk], acc[am][bn], 0, 0, 0);
    __builtin_amdgcn_s_setprio(0);
    BAR();

    // q1: 4 reads; stage Bh0(t+2); mfma am2-3
    #pragma unroll
    for (int am = 0; am < 2; ++am)
      #pragma unroll
      for (int kk = 0; kk < 2; ++kk)
        af[am][kk] = ld_frag(Al, (2 + am) * 16 + ln15, kk * 32 + kof);
    stage_half(Bb + (long)(n0 + 0) * K + tB * 64, K, L(d, 1, 0), wave, lane);
    BAR();
    __builtin_amdgcn_s_setprio(1);
    #pragma unroll
    for (int am = 0; am < 2; ++am)
      #pragma unroll
      for (int bn = 0; bn < 4; ++bn)
        #pragma unroll
        for (int kk = 0; kk < 2; ++kk)
          acc[2 + am][bn] = __builtin_amdgcn_mfma_f32_16x16x32_bf16(af[am][kk], bf[bn][kk], acc[2 + am][bn], 0, 0, 0);
    __builtin_amdgcn_s_setprio(0);
    BAR();

    // q2: 4 reads; stage Bh1(t+2); mfma am4-5
    #pragma unroll
    for (int am = 0; am < 2; ++am)
      #pragma unroll
      for (int kk = 0; kk < 2; ++kk)
        af[am][kk] = ld_frag(Al, (4 + am) * 16 + ln15, kk * 32 + kof);
    stage_half(Bb + (long)(n0 + 128) * K + tB * 64, K, L(d, 1, 1), wave, lane);
    BAR();
    __builtin_amdgcn_s_setprio(1);
    #pragma unroll
    for (int am = 0; am < 2; ++am)
      #pragma unroll
      for (int bn = 0; bn < 4; ++bn)
        #pragma unroll
        for (int kk = 0; kk < 2; ++kk)
          acc[4 + am][bn] = __builtin_amdgcn_mfma_f32_16x16x32_bf16(af[am][kk], bf[bn][kk], acc[4 + am][bn], 0, 0, 0);
    __builtin_amdgcn_s_setprio(0);
    BAR();

    // q3: 4 reads; mfma am6-7; per-tile vmcnt(4)
    #pragma unroll
    for (int am = 0; am < 2; ++am)
      #pragma unroll
      for (int kk = 0; kk < 2; ++kk)
        af[am][kk] = ld_frag(Al, (6 + am) * 16 + ln15, kk * 32 + kof);
    BAR();
    __builtin_amdgcn_s_setprio(1);
    #pragma unroll
    for (int am = 0; am < 2; ++am)
      #pragma unroll
      for (int bn = 0; bn < 4; ++bn)
        #pragma unroll
        for (int kk = 0; kk < 2; ++kk)
          acc[6 + am][bn] = __builtin_amdgcn_mfma_f32_16x16x32_bf16(af[am][kk], bf[bn][kk], acc[6 + am][bn], 0, 0, 0);
    __builtin_amdgcn_s_setprio(0);
    WAITV(4);
    BAR();
  }

  WAITV(0);
  BAR();

  // epilogue: C/D col=lane&15, row=(lane>>4)*4+r
  const int cl = lane & 15;
  const int rb = (lane >> 4) * 4;
  #pragma unroll
  for (int bn = 0; bn < 4; ++bn) {
    const int gcol = n0 + wn * 64 + bn * 16 + cl;
    const float badd = bias ? bias[gcol] : 0.f;
    #pragma unroll
    for (int am = 0; am < 8; ++am) {
      #pragma unroll
      for (int r = 0; r < 4; ++r) {
        const int grow = m0 + wm * 128 + am * 16 + rb + r;
        const float val = acc[am][bn][r] * scale + badd;
        if (OUT_MODE == 0) {
          ((float*)Cout)[(long)z * sC + (long)grow * N + gcol] = val;
        } else if (OUT_MODE == 1) {
          ((u16*)Cout)[(long)z * sC + (long)grow * N + gcol] = f2bf(val);
        } else if (OUT_MODE == 3) {
          ((u16*)Cout)[(long)z * sC + (long)grow * N + gcol] = f2h(val);
        } else {
          const int bb = grow >> 11, l2 = grow & 2047;
          ((u16*)Cout)[((long)bb * N + gcol) * 2048 + l2] = f2bf(val);
        }
      }
    }
  }
}

__global__ void __launch_bounds__(512, 2)
proj_gemm(const u16* A, const u16* Bt, void* C, const float* bias,
          int M, int N, int K, long sA, long sB, long sC, float scale) {
  __shared__ u16 lds[8 * 8192];
  gemm256_body<1>(A, Bt, C, bias, M, N, K, sA, sB, sC, scale, lds);
}
__global__ void __launch_bounds__(512, 2)
projv_gemm(const u16* A, const u16* Bt, void* C, const float* bias,
           int M, int N, int K, long sA, long sB, long sC, float scale) {
  __shared__ u16 lds[8 * 8192];
  gemm256_body<2>(A, Bt, C, bias, M, N, K, sA, sB, sC, scale, lds);
}
__global__ void __launch_bounds__(512, 2)
qk_gemm(const u16* A, const u16* Bt, void* C, const float* bias,
        int M, int N, int K, long sA, long sB, long sC, float scale) {
  __shared__ u16 lds[8 * 8192];
  gemm256_body<3>(A, Bt, C, bias, M, N, K, sA, sB, sC, scale, lds);
}
__global__ void __launch_bounds__(512, 2)
pv_gemm(const u16* A, const u16* Bt, void* C, const float* bias,
        int M, int N, int K, long sA, long sB, long sC, float scale) {
  __shared__ u16 lds[8 * 8192];
  gemm256_body<0>(A, Bt, C, bias, M, N, K, sA, sB, sC, scale, lds);
}

// softmax over fp16 S slab: blockIdx.x = row; mask batch = row>>11
__global__ void softmax_rows_h(const u16* __restrict__ S, const int* __restrict__ Km,
                               u16* __restrict__ P)
{
  const long row = blockIdx.x;
  const int b = (int)(row >> 11);
  const u16* s = S + row * 2048;
  const int* mask = Km + (long)b * 2048;
  u16* p = P + row * 2048;

  const int t = threadIdx.x;
  const int base = t * 8;

  ushort4 r0 = *reinterpret_cast<const ushort4*>(s + base);
  ushort4 r1 = *reinterpret_cast<const ushort4*>(s + base + 4);
  int4 mA = *reinterpret_cast<const int4*>(mask + base);
  int4 mB = *reinterpret_cast<const int4*>(mask + base + 4);

  float vals[8] = {h2f(r0.x), h2f(r0.y), h2f(r0.z), h2f(r0.w),
                   h2f(r1.x), h2f(r1.y), h2f(r1.z), h2f(r1.w)};
  const int mk[8] = {mA.x, mA.y, mA.z, mA.w, mB.x, mB.y, mB.z, mB.w};

  float mx = -3.0e38f;
  #pragma unroll
  for (int i = 0; i < 8; i++) if (!mk[i]) mx = fmaxf(mx, vals[i]);
  #pragma unroll
  for (int off = 32; off > 0; off >>= 1) mx = fmaxf(mx, __shfl_xor(mx, off));

  __shared__ float redm[4], reds[4];
  const int wave = t >> 6, lane = t & 63;
  if (lane == 0) redm[wave] = mx;
  __syncthreads();
  mx = fmaxf(fmaxf(redm[0], redm[1]), fmaxf(redm[2], redm[3]));

  float e[8]; float sum = 0.f;
  #pragma unroll
  for (int i = 0; i < 8; i++) { e[i] = mk[i] ? 0.f : __expf(vals[i] - mx); sum += e[i]; }
  #pragma unroll
  for (int off = 32; off > 0; off >>= 1) sum += __shfl_xor(sum, off);
  if (lane == 0) reds[wave] = sum;
  __syncthreads();
  sum = reds[0] + reds[1] + reds[2] + reds[3];
  const float inv = 1.f / sum;

  *reinterpret_cast<ushort4*>(p + base) =
      make_ushort4(f2bf(e[0]*inv), f2bf(e[1]*inv), f2bf(e[2]*inv), f2bf(e[3]*inv));
  *reinterpret_cast<ushort4*>(p + base + 4) =
      make_ushort4(f2bf(e[4]*inv), f2bf(e[5]*inv), f2bf(e[6]*inv), f2bf(e[7]*inv));
}

extern "C" void kernel_launch(void* const* d_in, const int* in_sizes, int n_in,
                              void* d_out, int out_size, void* d_ws, size_t ws_size,
                              hipStream_t stream) {
  (void)in_sizes; (void)n_in; (void)out_size;

  const float* Qin  = (const float*)d_in[0];
  const float* Kin  = (const float*)d_in[1];
  const float* Vin  = (const float*)d_in[2];
  const int*   Kmask = (const int*)d_in[3];
  const float* Wq = (const float*)d_in[4];
  const float* bq = (const float*)d_in[5];
  const float* Wk = (const float*)d_in[6];
  const float* bk = (const float*)d_in[7];
  const float* Wv = (const float*)d_in[8];
  const float* bv = (const float*)d_in[9];

  char* ws = (char*)d_ws;
  const size_t MB = 1024UL * 1024UL;
  const long NW = 1024L * 1024;
  const dim3 blk(256);
  const dim3 gblk(512);
  const float rs = 0.03125f;  // 1/sqrt(1024)

  if (ws_size >= 226 * MB) {
    // [0,32) qb  [32,64) kb  [64,96) vT
    // [96,160)  P bf16 / {Xq 96-128, Xk 128-160} during projections
    // [160,224) S fp16 all 8 batches / Xv 160-192 during projections
    // [224,226) Wb
    u16*  qb = (u16*)(ws);
    u16*  kb = (u16*)(ws + 32 * MB);
    u16*  vT = (u16*)(ws + 64 * MB);
    u16*  P  = (u16*)(ws + 96 * MB);
    u16*  Xq = (u16*)(ws + 96 * MB);     // 3x 16777216-elem slabs: 96/128/160
    u16*  S  = (u16*)(ws + 160 * MB);
    u16*  Wb = (u16*)(ws + 224 * MB);

    cvt3_f32_bf16<<<dim3(16384, 1, 3), blk, 0, stream>>>(Qin, Kin, Vin, Xq);

    cvt_f32_bf16<<<dim3(NW / 1024), blk, 0, stream>>>(Wq, Wb, NW);
    proj_gemm<<<dim3(4, 64, 1), gblk, 0, stream>>>(Xq, Wb, qb, bq,
        16384, 1024, 1024, 0, 0, 0, 1.f);

    cvt_f32_bf16<<<dim3(NW / 1024), blk, 0, stream>>>(Wk, Wb, NW);
    proj_gemm<<<dim3(4, 64, 1), gblk, 0, stream>>>(Xq + 16777216L, Wb, kb, bk,
        16384, 1024, 1024, 0, 0, 0, 1.f);

    cvt_f32_bf16<<<dim3(NW / 1024), blk, 0, stream>>>(Wv, Wb, NW);
    projv_gemm<<<dim3(4, 64, 1), gblk, 0, stream>>>(Xq + 2L * 16777216L, Wb, vT, bv,
        16384, 1024, 1024, 0, 0, 0, 1.f);

    // S = q k^T / 32 (fp16), all 8 batches in one dispatch
    qk_gemm<<<dim3(8, 8, 8), gblk, 0, stream>>>(qb, kb, S, nullptr,
        2048, 2048, 1024, 2048L * 1024, 2048L * 1024, 2048L * 2048, rs);
    softmax_rows_h<<<dim3(16384), blk, 0, stream>>>(S, Kmask, P);

    pv_gemm<<<dim3(4, 8, 8), gblk, 0, stream>>>(P, vT, d_out, nullptr,
        2048, 1024, 2048, 2048L * 2048, 1024L * 2048, 2048L * 1024, 1.f);
  } else if (ws_size >= 194 * MB) {
    // S fp16 4 batches (32MB) at 160-192; two qk/softmax passes
    u16*  qb = (u16*)(ws);
    u16*  kb = (u16*)(ws + 32 * MB);
    u16*  vT = (u16*)(ws + 64 * MB);
    u16*  P  = (u16*)(ws + 96 * MB);
    u16*  Xq = (u16*)(ws + 96 * MB);
    u16*  S  = (u16*)(ws + 160 * MB);
    u16*  Wb = (u16*)(ws + 192 * MB);

    cvt3_f32_bf16<<<dim3(16384, 1, 3), blk, 0, stream>>>(Qin, Kin, Vin, Xq);

    cvt_f32_bf16<<<dim3(NW / 1024), blk, 0, stream>>>(Wq, Wb, NW);
    proj_gemm<<<dim3(4, 64, 1), gblk, 0, stream>>>(Xq, Wb, qb, bq,
        16384, 1024, 1024, 0, 0, 0, 1.f);
    cvt_f32_bf16<<<dim3(NW / 1024), blk, 0, stream>>>(Wk, Wb, NW);
    proj_gemm<<<dim3(4, 64, 1), gblk, 0, stream>>>(Xq + 16777216L, Wb, kb, bk,
        16384, 1024, 1024, 0, 0, 0, 1.f);
    cvt_f32_bf16<<<dim3(NW / 1024), blk, 0, stream>>>(Wv, Wb, NW);
    projv_gemm<<<dim3(4, 64, 1), gblk, 0, stream>>>(Xq + 2L * 16777216L, Wb, vT, bv,
        16384, 1024, 1024, 0, 0, 0, 1.f);

    for (int h = 0; h < 2; h++) {
      const u16* qbH = qb + (long)(4 * h) * 2048 * 1024;
      const u16* kbH = kb + (long)(4 * h) * 2048 * 1024;
      qk_gemm<<<dim3(8, 8, 4), gblk, 0, stream>>>(qbH, kbH, S, nullptr,
          2048, 2048, 1024, 2048L * 1024, 2048L * 1024, 2048L * 2048, rs);
      softmax_rows_h<<<dim3(8192), blk, 0, stream>>>(
          S, Kmask + (long)(4 * h) * 2048, P + (long)(4 * h) * 2048 * 2048);
    }

    pv_gemm<<<dim3(4, 8, 8), gblk, 0, stream>>>(P, vT, d_out, nullptr,
        2048, 1024, 2048, 2048L * 2048, 1024L * 2048, 2048L * 1024, 1.f);
  } else {
    // 130 MB fallback: per-batch S/P streaming (S fp16 8MB, P 8MB)
    u16*  qb = (u16*)(ws);
    u16*  kb = (u16*)(ws + 32 * MB);
    u16*  vT = (u16*)(ws + 64 * MB);
    u16*  Xb = (u16*)(ws + 96 * MB);
    u16*  S  = (u16*)(ws + 96 * MB);
    u16*  P  = (u16*)(ws + 104 * MB);
    u16*  Wb = (u16*)(ws + 128 * MB);
    const long NQKV = 8L * 2048 * 1024;

    cvt_f32_bf16<<<dim3(NQKV / 1024), blk, 0, stream>>>(Qin, Xb, NQKV);
    cvt_f32_bf16<<<dim3(NW / 1024), blk, 0, stream>>>(Wq, Wb, NW);
    proj_gemm<<<dim3(4, 64, 1), gblk, 0, stream>>>(Xb, Wb, qb, bq,
        16384, 1024, 1024, 0, 0, 0, 1.f);
    cvt_f32_bf16<<<dim3(NQKV / 1024), blk, 0, stream>>>(Kin, Xb, NQKV);
    cvt_f32_bf16<<<dim3(NW / 1024), blk, 0, stream>>>(Wk, Wb, NW);
    proj_gemm<<<dim3(4, 64, 1), gblk, 0, stream>>>(Xb, Wb, kb, bk,
        16384, 1024, 1024, 0, 0, 0, 1.f);
    cvt_f32_bf16<<<dim3(NQKV / 1024), blk, 0, stream>>>(Vin, Xb, NQKV);
    cvt_f32_bf16<<<dim3(NW / 1024), blk, 0, stream>>>(Wv, Wb, NW);
    projv_gemm<<<dim3(4, 64, 1), gblk, 0, stream>>>(Xb, Wb, vT, bv,
        16384, 1024, 1024, 0, 0, 0, 1.f);

    for (int b = 0; b < 8; b++) {
      const u16* qbB = qb + (long)b * 2048 * 1024;
      const u16* kbB = kb + (long)b * 2048 * 1024;
      const u16* vTB = vT + (long)b * 1024 * 2048;
      float* outB = (float*)d_out + (long)b * 2048 * 1024;

      qk_gemm<<<dim3(8, 8, 1), gblk, 0, stream>>>(qbB, kbB, S, nullptr,
          2048, 2048, 1024, 0, 0, 0, rs);
      softmax_rows_h<<<dim3(2048), blk, 0, stream>>>(S, Kmask + (long)b * 2048, P);
      pv_gemm<<<dim3(4, 8, 1), gblk, 0, stream>>>(P, vTB, outB, nullptr,
          2048, 1024, 2048, 0, 0, 0, 1.f);
    }
  }
}